// Round 2
// baseline (1217.468 us; speedup 1.0000x reference)
//
#include <hip/hip_runtime.h>
#include <hip/hip_bf16.h>

#define HID 2048
#define NEXP 8
#define MINTER 1408
#define SINTER 5632
#define MTOK 4096
#define CAP 4096
#define BK 64

typedef short bf16x8 __attribute__((ext_vector_type(8)));
typedef float floatx4 __attribute__((ext_vector_type(4)));

__device__ __forceinline__ unsigned short f2bf_rn(float f) {
    union { float f; unsigned u; } v; v.f = f;
    unsigned r = v.u + 0x7FFFu + ((v.u >> 16) & 1u);
    return (unsigned short)(r >> 16);
}

__device__ __forceinline__ unsigned pack_bf16x2(float a, float b) {
    __hip_bfloat162 h = __float22bfloat162_rn(make_float2(a, b));
    unsigned u;
    __builtin_memcpy(&u, &h, 4);
    return u;
}

// async global->LDS, 16B per lane; lds dest must be wave-uniform base (+lane*16 by HW)
__device__ __forceinline__ void async16(const unsigned short* g, unsigned short* l) {
    __builtin_amdgcn_global_load_lds(
        (const __attribute__((address_space(1))) unsigned int*)(g),
        (__attribute__((address_space(3))) unsigned int*)(l),
        16, 0, 0);
}

// ---------------- fp32 -> bf16 cast ----------------
__global__ void cvt_kernel(const float* __restrict__ x, unsigned short* __restrict__ xb) {
    size_t i = ((size_t)blockIdx.x * 256 + threadIdx.x) * 4;
    float4 v = *(const float4*)(x + i);
    uint2 pk;
    pk.x = pack_bf16x2(v.x, v.y);
    pk.y = pack_bf16x2(v.z, v.w);
    *(uint2*)(xb + i) = pk;
}

// fp32 -> bf16 cast with gate/up ROW INTERLEAVE per expert:
// input row j in [0,2S): j<S (gate) -> out row 2j ; j>=S (up) -> out row 2(j-S)+1.
// Makes gate col c and up col c sit at output cols 2c / 2c+1 (lane pairs in MFMA C layout).
template <int S, int RTOT>
__global__ void cvt_inter_kernel(const float* __restrict__ x, unsigned short* __restrict__ xb) {
    size_t i0 = (size_t)blockIdx.x * 1024;          // one block = half of one 2048-col row
    int row = (int)(i0 >> 11);
    int e = row / RTOT;
    int j = row - e * RTOT;
    int nj = (j < S) ? (2 * j) : (2 * (j - S) + 1);
    size_t src = i0 + (size_t)threadIdx.x * 4;
    size_t dst = (((size_t)(e * RTOT + nj)) << 11) + (i0 & 2047) + (size_t)threadIdx.x * 4;
    float4 v = *(const float4*)(x + src);
    uint2 pk;
    pk.x = pack_bf16x2(v.x, v.y);
    pk.y = pack_bf16x2(v.z, v.w);
    *(uint2*)(xb + dst) = pk;
}

// ---------------- router + shared gate ----------------
__global__ void router_kernel(const float* __restrict__ x, const float* __restrict__ gw,
                              const float* __restrict__ sgw,
                              float* __restrict__ tok2w, float* __restrict__ gate_sig,
                              int* __restrict__ counts, int* __restrict__ tok_list) {
    int wid = threadIdx.x >> 6, lane = threadIdx.x & 63;
    int tok = blockIdx.x * 4 + wid;
    const float* xr = x + (size_t)tok * HID;
    float acc[9];
#pragma unroll
    for (int e = 0; e < 9; e++) acc[e] = 0.f;
    for (int i = lane; i < HID; i += 64) {
        float xv = xr[i];
#pragma unroll
        for (int e = 0; e < NEXP; e++) acc[e] += xv * gw[e * HID + i];
        acc[8] += xv * sgw[i];
    }
#pragma unroll
    for (int e = 0; e < 9; e++) {
#pragma unroll
        for (int off = 32; off; off >>= 1) acc[e] += __shfl_down(acc[e], off);
    }
    if (lane == 0) {
        float m = acc[0];
#pragma unroll
        for (int e = 1; e < NEXP; e++) m = fmaxf(m, acc[e]);
        float ex[NEXP]; float s = 0.f;
#pragma unroll
        for (int e = 0; e < NEXP; e++) { ex[e] = __expf(acc[e] - m); s += ex[e]; }
        int e1 = 0; float b1 = ex[0];
#pragma unroll
        for (int e = 1; e < NEXP; e++) if (ex[e] > b1) { b1 = ex[e]; e1 = e; }
        int e2 = -1; float b2 = -1.f;
#pragma unroll
        for (int e = 0; e < NEXP; e++) {
            if (e == e1) continue;
            if (ex[e] > b2) { b2 = ex[e]; e2 = e; }
        }
        float inv = 1.f / s;
        int p = atomicAdd(&counts[e1], 1);
        tok_list[e1 * CAP + p] = tok * 2;
        tok2w[tok * 2] = b1 * inv;
        p = atomicAdd(&counts[e2], 1);
        tok_list[e2 * CAP + p] = tok * 2 + 1;
        tok2w[tok * 2 + 1] = b2 * inv;
        gate_sig[tok] = 1.f / (1.f + __expf(-acc[8]));
    }
}

// =================== 256x256 8-phase pipelined GEMM ===================
// 512 threads (8 waves: wm=w>>2 over M-halves, wn=w&3 over N). LDS: 8 regions of
// 16KB (128 rows x 64 k bf16): A[buf][half] at 0..64KB, B[buf][half] at 64..128KB.
// Per K-tile: 4 phases = C-quadrants (0,0)(0,1)(1,0)(1,1). Region last-read phases:
// A0:P2 B0:P3 A1:P4 B1:P4. Issue schedule (each overwrite strictly AFTER the
// barrier closing its last-read phase):
//   P1(t): A1[nb] (tile t+1) | P2(t): B1[nb] (t+1) | P3(t): A0[b] (t+2) | P4(t): B0[b] (t+2)
// Waits: vmcnt(6) at end-P1 and end-P4 (3 regions stay in flight across every
// barrier; each waited load is >=3 phases old). Induction: end-P4(t) covers
// A0[nb],B0[nb],A1[nb] (reads P1/P3 of t+1); end-P1(t+1) covers B1[nb] (reads P2/P4).
// Prologue: A0(0),B0(0),B1(0),A1(0),A0(1),B0(1); vmcnt(8) -> tile-0 P1 safe; the
// in-loop waits cover the rest. Tail prefetches overrun K by <=2 tiles (reads land
// in adjacent workspace allocations - harmless); vmcnt(0) before epilogue.
// LDS chunk-XOR swizzle: chunk slot ch holds global chunk (ch ^ (row&7)) - the
// verified conflict-free layout (SQ_LDS_BANK_CONFLICT == 0).
//
// MODE 0: shared gate_up (interleaved) -> silu*mul pairs -> bf16 inter      (K=2048)
// MODE 1: moe w13 (interleaved, gathered rows) -> bf16 inter[entry][1408]   (K=2048)
// MODE 2: shared down, split-K (z in 0..1, 2816 each), atomicAdd*sigmoid    (K=5632)
// MODE 3: moe w2 (gathered), atomicAdd * routing weight                     (K=1408)

#define VMCNT6 asm volatile("s_waitcnt vmcnt(6)" ::: "memory")
#define VMCNT8 asm volatile("s_waitcnt vmcnt(8)" ::: "memory")
#define VMCNT0 asm volatile("s_waitcnt vmcnt(0)" ::: "memory")
#define BARRIER __builtin_amdgcn_s_barrier()

#define ISS(p0, p1, dst) { async16(p0, (dst) + w512); async16(p1, (dst) + 4096 + w512); p0 += BK; p1 += BK; }
#define ISS_A0(bb) ISS(pA00, pA01, smem + ((bb) * 2 + 0) * 8192)
#define ISS_A1(bb) ISS(pA10, pA11, smem + ((bb) * 2 + 1) * 8192)
#define ISS_B0(bb) ISS(pB00, pB01, smem + 32768 + ((bb) * 2 + 0) * 8192)
#define ISS_B1(bb) ISS(pB10, pB11, smem + 32768 + ((bb) * 2 + 1) * 8192)

#define PHASE(QM, QN, ISSUE_STMT) {                                           \
    const unsigned short* la = smem + ((b * 2 + QM) * 8192);                  \
    const unsigned short* lb = smem + 32768 + ((b * 2 + QN) * 8192);          \
    bf16x8 af0[4], af1[4], bq0[2], bq1[2];                                    \
    _Pragma("unroll") for (int mt = 0; mt < 4; mt++) {                        \
        af0[mt] = *(const bf16x8*)(la + aoff[mt] + sl0);                      \
        af1[mt] = *(const bf16x8*)(la + aoff[mt] + sl1);                      \
    }                                                                         \
    _Pragma("unroll") for (int nt = 0; nt < 2; nt++) {                        \
        bq0[nt] = *(const bf16x8*)(lb + boff[nt] + sl0);                      \
        bq1[nt] = *(const bf16x8*)(lb + boff[nt] + sl1);                      \
    }                                                                         \
    ISSUE_STMT;                                                               \
    BARRIER;                                                                  \
    __builtin_amdgcn_s_setprio(1);                                            \
    _Pragma("unroll") for (int mt = 0; mt < 4; mt++)                          \
    _Pragma("unroll") for (int nt = 0; nt < 2; nt++)                          \
        acc[QM][QN][mt][nt] = __builtin_amdgcn_mfma_f32_16x16x32_bf16(        \
            af0[mt], bq0[nt], acc[QM][QN][mt][nt], 0, 0, 0);                  \
    _Pragma("unroll") for (int mt = 0; mt < 4; mt++)                          \
    _Pragma("unroll") for (int nt = 0; nt < 2; nt++)                          \
        acc[QM][QN][mt][nt] = __builtin_amdgcn_mfma_f32_16x16x32_bf16(        \
            af1[mt], bq1[nt], acc[QM][QN][mt][nt], 0, 0, 0);                  \
    __builtin_amdgcn_s_setprio(0);                                            \
}

template <int STRIDE, int KLEN, int MODE>
__global__ __launch_bounds__(512, 2) void gemm8(
    const unsigned short* __restrict__ A, const unsigned short* __restrict__ B,
    void* __restrict__ outp, const int* __restrict__ tok_list,
    const int* __restrict__ counts, const float* __restrict__ tok2w,
    const float* __restrict__ gate_sig)
{
    constexpr bool GATHER = (MODE == 1 || MODE == 3);
    constexpr int KT = KLEN / BK;
    __shared__ __align__(16) unsigned short smem[65536];   // 128 KB

    const int e = GATHER ? blockIdx.z : 0;
    int cnt = 0;
    int bx = blockIdx.x, by = blockIdx.y;
    if constexpr (MODE == 0 || MODE == 2) {
        // bijective XCD swizzle (grid sizes 704 / 128 are both % 8 == 0)
        const int nx = gridDim.x;
        const int nwg = nx * gridDim.y;
        int flat = by * nx + bx;
        const int qq = nwg >> 3;
        flat = (flat & 7) * qq + (flat >> 3);
        bx = flat % nx; by = flat / nx;
    }
    int r0 = by * 256;
    if constexpr (GATHER) {
        cnt = counts[e];
        if (r0 >= cnt) return;
    }
    const int bn0 = bx * 256;

    const int tid = threadIdx.x, lane = tid & 63, w = tid >> 6;
    const int r8 = lane >> 3, ch = lane & 7;
    const int swz = (ch ^ r8) << 3;          // pre-swizzled global chunk for linear LDS dest
    const int w512 = w << 9;                 // wave's 8-row slice within a 64-row stage call

    size_t koff = 0;
    if constexpr (MODE == 2) koff = (size_t)blockIdx.z * 2816;

    const unsigned short* Bb = B;
    if constexpr (MODE == 1) Bb += (size_t)e * (2 * MINTER) * HID;
    if constexpr (MODE == 3) Bb += (size_t)e * HID * MINTER;

    auto arow = [&](int h, int c) -> const unsigned short* {
        int rit = h * 128 + c * 64 + (w << 3) + r8;
        int grow;
        if constexpr (GATHER) {
            int idx = r0 + rit; if (idx > cnt - 1) idx = cnt - 1;
            int ent = tok_list[e * CAP + idx];
            grow = (MODE == 1) ? (ent >> 1) : ent;
        } else {
            grow = r0 + rit;
        }
        return A + (size_t)grow * STRIDE + koff + swz;
    };
    auto brow = [&](int h, int c) -> const unsigned short* {
        int rr = bn0 + h * 128 + c * 64 + (w << 3) + r8;
        return Bb + (size_t)rr * STRIDE + koff + swz;
    };
    const unsigned short *pA00 = arow(0, 0), *pA01 = arow(0, 1);
    const unsigned short *pA10 = arow(1, 0), *pA11 = arow(1, 1);
    const unsigned short *pB00 = brow(0, 0), *pB01 = brow(0, 1);
    const unsigned short *pB10 = brow(1, 0), *pB11 = brow(1, 1);

    const int m16 = lane & 15, quad = lane >> 4, m7 = m16 & 7;
    const int wm = w >> 2, wn = w & 3;
    int aoff[4], boff[2];
#pragma unroll
    for (int mt = 0; mt < 4; mt++) aoff[mt] = (wm * 64 + mt * 16 + m16) * BK;
#pragma unroll
    for (int nt = 0; nt < 2; nt++) boff[nt] = (wn * 32 + nt * 16 + m16) * BK;
    const int sl0 = ((0 * 4 + quad) ^ m7) << 3;
    const int sl1 = ((1 * 4 + quad) ^ m7) << 3;

    floatx4 acc[2][2][4][2];
#pragma unroll
    for (int i = 0; i < 2; i++)
#pragma unroll
        for (int j = 0; j < 2; j++)
#pragma unroll
            for (int mt = 0; mt < 4; mt++)
#pragma unroll
                for (int nt = 0; nt < 2; nt++)
                    acc[i][j][mt][nt] = floatx4{0.f, 0.f, 0.f, 0.f};

    // prologue: tile 0 all 4 regions + {A0,B0} of tile 1; vmcnt(8) lands tile-0
    // P1 regions (A0,B0); B1(0)/A1(0) are covered by the first in-loop vmcnt(6).
    ISS_A0(0); ISS_B0(0); ISS_B1(0); ISS_A1(0);
    ISS_A0(1); ISS_B0(1);
    VMCNT8; BARRIER;

    for (int t = 0; t < KT; t++) {
        const int b = t & 1, nb = b ^ 1;
        PHASE(0, 0, ISS_A1(nb));     // A1[nb]: last read P4(t-1) -> safe
        VMCNT6; BARRIER;             // covers B1[b] issued P2(t-1) for this tile's P2/P4
        PHASE(0, 1, ISS_B1(nb));     // B1[nb]: last read P4(t-1) -> safe
        BARRIER;
        PHASE(1, 0, ISS_A0(b));      // A0[b]: last read P2(t) -> safe
        BARRIER;
        PHASE(1, 1, ISS_B0(b));      // B0[b]: last read P3(t) -> safe
        VMCNT6; BARRIER;             // covers A0[nb],B0[nb],A1[nb] for next tile's P1/P3
    }
    VMCNT0;   // drain tail prefetches before LDS dealloc / wave exit

    // ---------------- epilogues ----------------
    if constexpr (MODE == 0) {
        unsigned short* sout = (unsigned short*)outp;
#pragma unroll
        for (int qm = 0; qm < 2; qm++)
#pragma unroll
        for (int mt = 0; mt < 4; mt++) {
            const int rb = r0 + qm * 128 + wm * 64 + mt * 16 + quad * 4;
#pragma unroll
            for (int qn = 0; qn < 2; qn++)
#pragma unroll
            for (int nt = 0; nt < 2; nt++) {
                const int col = bn0 + qn * 128 + wn * 32 + nt * 16 + m16;
#pragma unroll
                for (int r = 0; r < 4; r++) {
                    float v = acc[qm][qn][mt][nt][r];
                    float o = __shfl_xor(v, 1);          // partner (gate<->up) column
                    if (!(m16 & 1))
                        sout[(size_t)(rb + r) * SINTER + (col >> 1)] =
                            f2bf_rn(v / (1.f + __expf(-v)) * o);
                }
            }
        }
    } else if constexpr (MODE == 1) {
        unsigned short* sout = (unsigned short*)outp;
#pragma unroll
        for (int qm = 0; qm < 2; qm++)
#pragma unroll
        for (int mt = 0; mt < 4; mt++) {
            const int ib = r0 + qm * 128 + wm * 64 + mt * 16 + quad * 4;
            int ent[4]; bool val[4];
#pragma unroll
            for (int r = 0; r < 4; r++) {
                val[r] = (ib + r) < cnt;
                ent[r] = val[r] ? tok_list[e * CAP + ib + r] : 0;
            }
#pragma unroll
            for (int qn = 0; qn < 2; qn++)
#pragma unroll
            for (int nt = 0; nt < 2; nt++) {
                const int col = bn0 + qn * 128 + wn * 32 + nt * 16 + m16;
#pragma unroll
                for (int r = 0; r < 4; r++) {
                    float v = acc[qm][qn][mt][nt][r];
                    float o = __shfl_xor(v, 1);
                    if (val[r] && !(m16 & 1))
                        sout[(size_t)ent[r] * MINTER + (col >> 1)] =
                            f2bf_rn(v / (1.f + __expf(-v)) * o);
                }
            }
        }
    } else if constexpr (MODE == 2) {
        float* fout = (float*)outp;
#pragma unroll
        for (int qm = 0; qm < 2; qm++)
#pragma unroll
        for (int mt = 0; mt < 4; mt++) {
            const int rb = r0 + qm * 128 + wm * 64 + mt * 16 + quad * 4;
            float gs[4];
#pragma unroll
            for (int r = 0; r < 4; r++) gs[r] = gate_sig[rb + r];
#pragma unroll
            for (int qn = 0; qn < 2; qn++)
#pragma unroll
            for (int nt = 0; nt < 2; nt++) {
                const int col = bn0 + qn * 128 + wn * 32 + nt * 16 + m16;
#pragma unroll
                for (int r = 0; r < 4; r++)
                    unsafeAtomicAdd(&fout[(size_t)(rb + r) * HID + col],
                                    acc[qm][qn][mt][nt][r] * gs[r]);
            }
        }
    } else {
        float* fout = (float*)outp;
#pragma unroll
        for (int qm = 0; qm < 2; qm++)
#pragma unroll
        for (int mt = 0; mt < 4; mt++) {
            const int ib = r0 + qm * 128 + wm * 64 + mt * 16 + quad * 4;
            int tokv[4]; float wv[4]; bool val[4];
#pragma unroll
            for (int r = 0; r < 4; r++) {
                val[r] = (ib + r) < cnt;
                if (val[r]) {
                    int ent = tok_list[e * CAP + ib + r];
                    tokv[r] = ent >> 1;
                    wv[r] = tok2w[ent];
                } else { tokv[r] = 0; wv[r] = 0.f; }
            }
#pragma unroll
            for (int qn = 0; qn < 2; qn++)
#pragma unroll
            for (int nt = 0; nt < 2; nt++) {
                const int col = bn0 + qn * 128 + wn * 32 + nt * 16 + m16;
#pragma unroll
                for (int r = 0; r < 4; r++) {
                    if (val[r])
                        unsafeAtomicAdd(&fout[(size_t)tokv[r] * HID + col],
                                        acc[qm][qn][mt][nt][r] * wv[r]);
                }
            }
        }
    }
}

extern "C" void kernel_launch(void* const* d_in, const int* in_sizes, int n_in,
                              void* d_out, int out_size, void* d_ws, size_t ws_size,
                              hipStream_t stream) {
    const float* x    = (const float*)d_in[0];
    const float* gw   = (const float*)d_in[1];
    const float* sgw  = (const float*)d_in[2];
    const float* sgup = (const float*)d_in[3];
    const float* sdwn = (const float*)d_in[4];
    const float* w13  = (const float*)d_in[5];
    const float* w2   = (const float*)d_in[6];
    float* out = (float*)d_out;

    const size_t N_SGUP = (size_t)2 * SINTER * HID;        // 23,068,672
    const size_t N_SDWN = (size_t)HID * SINTER;            // 11,534,336
    const size_t N_W13  = (size_t)NEXP * 2 * MINTER * HID; // 46,137,344
    const size_t N_W2   = (size_t)NEXP * HID * MINTER;     // 23,068,672

    char* p = (char*)d_ws;
    unsigned short* xb = (unsigned short*)p;     p += (size_t)MTOK * HID * 2;        // 16 MB
    unsigned short* inter = (unsigned short*)p;  p += (size_t)MTOK * SINTER * 2;     // 46 MB (union)
    unsigned short* wbuf = (unsigned short*)p;   p += (N_W13 + N_W2) * 2;            // 138 MB (union)
    float* tok2w = (float*)p;                    p += (size_t)MTOK * 2 * 4;
    float* gate_sig = (float*)p;                 p += (size_t)MTOK * 4;
    int* tok_list = (int*)p;                     p += (size_t)NEXP * CAP * 4;
    int* counts = (int*)p;                       p += 64;

    // phase A weight views (overwritten in phase B after shared expert is done)
    unsigned short* sgup_b = wbuf;
    unsigned short* sdwn_b = wbuf + N_SGUP;
    // phase B weight views
    unsigned short* w13_b = wbuf;
    unsigned short* w2_b  = wbuf + N_W13;

    hipMemsetAsync(counts, 0, NEXP * sizeof(int), stream);
    // out is accumulated into (MODE2 split-K + MODE3), must start at zero
    hipMemsetAsync(out, 0, (size_t)MTOK * HID * sizeof(float), stream);

    cvt_kernel<<<(MTOK * HID) / 1024, 256, 0, stream>>>(x, xb);
    router_kernel<<<MTOK / 4, 256, 0, stream>>>(x, gw, sgw, tok2w, gate_sig, counts, tok_list);

    // ---- shared expert ----
    cvt_inter_kernel<SINTER, 2 * SINTER><<<N_SGUP / 1024, 256, 0, stream>>>(sgup, sgup_b);
    cvt_kernel<<<N_SDWN / 1024, 256, 0, stream>>>(sdwn, sdwn_b);
    gemm8<HID, HID, 0><<<dim3(2 * SINTER / 256, MTOK / 256), 512, 0, stream>>>(
        xb, sgup_b, inter, nullptr, nullptr, nullptr, nullptr);
    gemm8<SINTER, 2816, 2><<<dim3(HID / 256, MTOK / 256, 2), 512, 0, stream>>>(
        inter, sdwn_b, out, nullptr, nullptr, nullptr, gate_sig);

    // ---- MoE experts (reuse wbuf + inter) ----
    cvt_inter_kernel<MINTER, 2 * MINTER><<<N_W13 / 1024, 256, 0, stream>>>(w13, w13_b);
    cvt_kernel<<<N_W2 / 1024, 256, 0, stream>>>(w2, w2_b);
    gemm8<HID, HID, 1><<<dim3(2 * MINTER / 256, CAP / 256, NEXP), 512, 0, stream>>>(
        xb, w13_b, inter, tok_list, counts, nullptr, nullptr);
    gemm8<MINTER, MINTER, 3><<<dim3(HID / 256, CAP / 256, NEXP), 512, 0, stream>>>(
        inter, w2_b, out, tok_list, counts, tok2w, nullptr);
}

// Round 3
// 1185.289 us; speedup vs baseline: 1.0271x; 1.0271x over previous
//
#include <hip/hip_runtime.h>
#include <hip/hip_bf16.h>

#define HID 2048
#define NEXP 8
#define MINTER 1408
#define SINTER 5632
#define MTOK 4096
#define CAP 4096
#define BK 64

typedef short bf16x8 __attribute__((ext_vector_type(8)));
typedef float floatx4 __attribute__((ext_vector_type(4)));

__device__ __forceinline__ unsigned short f2bf_rn(float f) {
    union { float f; unsigned u; } v; v.f = f;
    unsigned r = v.u + 0x7FFFu + ((v.u >> 16) & 1u);
    return (unsigned short)(r >> 16);
}

__device__ __forceinline__ unsigned pack_bf16x2(float a, float b) {
    __hip_bfloat162 h = __float22bfloat162_rn(make_float2(a, b));
    unsigned u;
    __builtin_memcpy(&u, &h, 4);
    return u;
}

// async global->LDS, 16B per lane; lds dest must be wave-uniform base (+lane*16 by HW)
__device__ __forceinline__ void async16(const unsigned short* g, unsigned short* l) {
    __builtin_amdgcn_global_load_lds(
        (const __attribute__((address_space(1))) unsigned int*)(g),
        (__attribute__((address_space(3))) unsigned int*)(l),
        16, 0, 0);
}

// ---------------- fp32 -> bf16 cast ----------------
__global__ void cvt_kernel(const float* __restrict__ x, unsigned short* __restrict__ xb) {
    size_t i = ((size_t)blockIdx.x * 256 + threadIdx.x) * 4;
    float4 v = *(const float4*)(x + i);
    uint2 pk;
    pk.x = pack_bf16x2(v.x, v.y);
    pk.y = pack_bf16x2(v.z, v.w);
    *(uint2*)(xb + i) = pk;
}

// fp32 -> bf16 cast with gate/up ROW INTERLEAVE per expert:
// input row j in [0,2S): j<S (gate) -> out row 2j ; j>=S (up) -> out row 2(j-S)+1.
template <int S, int RTOT>
__global__ void cvt_inter_kernel(const float* __restrict__ x, unsigned short* __restrict__ xb) {
    size_t i0 = (size_t)blockIdx.x * 1024;          // one block = half of one 2048-col row
    int row = (int)(i0 >> 11);
    int e = row / RTOT;
    int j = row - e * RTOT;
    int nj = (j < S) ? (2 * j) : (2 * (j - S) + 1);
    size_t src = i0 + (size_t)threadIdx.x * 4;
    size_t dst = (((size_t)(e * RTOT + nj)) << 11) + (i0 & 2047) + (size_t)threadIdx.x * 4;
    float4 v = *(const float4*)(x + src);
    uint2 pk;
    pk.x = pack_bf16x2(v.x, v.y);
    pk.y = pack_bf16x2(v.z, v.w);
    *(uint2*)(xb + dst) = pk;
}

// ---------------- router + shared gate ----------------
__global__ void router_kernel(const float* __restrict__ x, const float* __restrict__ gw,
                              const float* __restrict__ sgw,
                              float* __restrict__ tok2w, float* __restrict__ gate_sig,
                              int* __restrict__ counts, int* __restrict__ tok_list) {
    int wid = threadIdx.x >> 6, lane = threadIdx.x & 63;
    int tok = blockIdx.x * 4 + wid;
    const float* xr = x + (size_t)tok * HID;
    float acc[9];
#pragma unroll
    for (int e = 0; e < 9; e++) acc[e] = 0.f;
    for (int i = lane; i < HID; i += 64) {
        float xv = xr[i];
#pragma unroll
        for (int e = 0; e < NEXP; e++) acc[e] += xv * gw[e * HID + i];
        acc[8] += xv * sgw[i];
    }
#pragma unroll
    for (int e = 0; e < 9; e++) {
#pragma unroll
        for (int off = 32; off; off >>= 1) acc[e] += __shfl_down(acc[e], off);
    }
    if (lane == 0) {
        float m = acc[0];
#pragma unroll
        for (int e = 1; e < NEXP; e++) m = fmaxf(m, acc[e]);
        float ex[NEXP]; float s = 0.f;
#pragma unroll
        for (int e = 0; e < NEXP; e++) { ex[e] = __expf(acc[e] - m); s += ex[e]; }
        int e1 = 0; float b1 = ex[0];
#pragma unroll
        for (int e = 1; e < NEXP; e++) if (ex[e] > b1) { b1 = ex[e]; e1 = e; }
        int e2 = -1; float b2 = -1.f;
#pragma unroll
        for (int e = 0; e < NEXP; e++) {
            if (e == e1) continue;
            if (ex[e] > b2) { b2 = ex[e]; e2 = e; }
        }
        float inv = 1.f / s;
        int p = atomicAdd(&counts[e1], 1);
        tok_list[e1 * CAP + p] = tok * 2;
        tok2w[tok * 2] = b1 * inv;
        p = atomicAdd(&counts[e2], 1);
        tok_list[e2 * CAP + p] = tok * 2 + 1;
        tok2w[tok * 2 + 1] = b2 * inv;
        gate_sig[tok] = 1.f / (1.f + __expf(-acc[8]));
    }
}

// =================== 256x256 8-phase pipelined GEMM (snake order + reg reuse) ===
// 512 threads (8 waves: wm=w>>2 over M-halves, wn=w&3 over N). LDS: 8 regions of
// 16KB (128 rows x 64 k bf16): A[buf][half] at 0..64KB, B[buf][half] at 64..128KB.
// Quadrant SNAKE order per K-tile: P1=(0,0) P2=(0,1) P3=(1,1) P4=(1,0).
// Register reuse across phases: P2 reuses af(A0), P3 reuses bq(B1), P4 reuses af(A1)
// -> ds_read_b128 per wave per K-tile = 12+4+8+4 = 28 (was 48).
// LDS last-read phases: A0:P1  B1:P2  A1:P3  B0:P4 (B0 read in P1 and P4).
// Issue schedule (one region = 2 global_load_lds per phase, each >=1 barrier after
// that region's last LDS read):
//   P1(t): B0[nb] (tile t+1) | P2(t): A0[b] (t+2) | P3(t): B1[b] (t+2) | P4(t): A1[b] (t+2)
// Waits: ONE hard vmcnt(6) at end-P4: 14 outstanding there, the 8 oldest are exactly
// tile t+1's four regions (ages 4-7 phases ~ >1000 cy -> no stall). vmcnt(10) at
// end-P1/end-P2 lands B1[0]/A1[0] for tile 0 only; provable no-op in steady state
// (<=8 / <=10 outstanding). Prologue stages 7 regions: tile0 x4 + A0/B1/A1 of tile1
// (B0[1] comes from P1(0)); vmcnt(10) lands A0[0],B0[0].
// Tail prefetches overrun K by <=2 tiles (reads land in adjacent workspace
// allocations - harmless); vmcnt(0) before epilogue (wave-exit safety).
// LDS chunk-XOR swizzle: chunk slot ch holds global chunk (ch ^ (row&7)) - verified
// conflict-free (SQ_LDS_BANK_CONFLICT == 0).
//
// MODE 0: shared gate_up (interleaved) -> silu*mul pairs -> bf16 inter      (K=2048)
// MODE 1: moe w13 (interleaved, gathered rows) -> bf16 inter[entry][1408]   (K=2048)
// MODE 2: shared down, split-K (z in 0..1, 2816 each), atomicAdd*sigmoid    (K=5632)
// MODE 3: moe w2 (gathered), atomicAdd * routing weight                     (K=1408)

#define VMCNT6  asm volatile("s_waitcnt vmcnt(6)" ::: "memory")
#define VMCNT10 asm volatile("s_waitcnt vmcnt(10)" ::: "memory")
#define VMCNT0  asm volatile("s_waitcnt vmcnt(0)" ::: "memory")
#define BARRIER __builtin_amdgcn_s_barrier()

#define ISS(p0, p1, dst) { async16(p0, (dst) + w512); async16(p1, (dst) + 4096 + w512); p0 += BK; p1 += BK; }
#define ISS_A0(bb) ISS(pA00, pA01, smem + ((bb) * 2 + 0) * 8192)
#define ISS_A1(bb) ISS(pA10, pA11, smem + ((bb) * 2 + 1) * 8192)
#define ISS_B0(bb) ISS(pB00, pB01, smem + 32768 + ((bb) * 2 + 0) * 8192)
#define ISS_B1(bb) ISS(pB10, pB11, smem + 32768 + ((bb) * 2 + 1) * 8192)

#define LD_A(LA) {                                                            \
    _Pragma("unroll") for (int mt = 0; mt < 4; mt++) {                        \
        af0[mt] = *(const bf16x8*)((LA) + aoff[mt] + sl0);                    \
        af1[mt] = *(const bf16x8*)((LA) + aoff[mt] + sl1);                    \
    } }
#define LD_B(LB) {                                                            \
    _Pragma("unroll") for (int nt = 0; nt < 2; nt++) {                        \
        bq0[nt] = *(const bf16x8*)((LB) + boff[nt] + sl0);                    \
        bq1[nt] = *(const bf16x8*)((LB) + boff[nt] + sl1);                    \
    } }
#define MFMA16(QM, QN) {                                                      \
    __builtin_amdgcn_s_setprio(1);                                            \
    _Pragma("unroll") for (int mt = 0; mt < 4; mt++)                          \
    _Pragma("unroll") for (int nt = 0; nt < 2; nt++)                          \
        acc[QM][QN][mt][nt] = __builtin_amdgcn_mfma_f32_16x16x32_bf16(        \
            af0[mt], bq0[nt], acc[QM][QN][mt][nt], 0, 0, 0);                  \
    _Pragma("unroll") for (int mt = 0; mt < 4; mt++)                          \
    _Pragma("unroll") for (int nt = 0; nt < 2; nt++)                          \
        acc[QM][QN][mt][nt] = __builtin_amdgcn_mfma_f32_16x16x32_bf16(        \
            af1[mt], bq1[nt], acc[QM][QN][mt][nt], 0, 0, 0);                  \
    __builtin_amdgcn_s_setprio(0);                                            \
}

template <int STRIDE, int KLEN, int MODE>
__global__ __launch_bounds__(512, 2) void gemm8(
    const unsigned short* __restrict__ A, const unsigned short* __restrict__ B,
    void* __restrict__ outp, const int* __restrict__ tok_list,
    const int* __restrict__ counts, const float* __restrict__ tok2w,
    const float* __restrict__ gate_sig)
{
    constexpr bool GATHER = (MODE == 1 || MODE == 3);
    constexpr int KT = KLEN / BK;
    __shared__ __align__(16) unsigned short smem[65536];   // 128 KB

    const int e = GATHER ? blockIdx.z : 0;
    int cnt = 0;
    int bx = blockIdx.x, by = blockIdx.y;
    if constexpr (MODE == 0 || MODE == 2) {
        // bijective XCD swizzle (grid sizes 704 / 128 are both % 8 == 0)
        const int nx = gridDim.x;
        const int nwg = nx * gridDim.y;
        int flat = by * nx + bx;
        const int qq = nwg >> 3;
        flat = (flat & 7) * qq + (flat >> 3);
        bx = flat % nx; by = flat / nx;
    }
    int r0 = by * 256;
    if constexpr (GATHER) {
        cnt = counts[e];
        if (r0 >= cnt) return;
    }
    const int bn0 = bx * 256;

    const int tid = threadIdx.x, lane = tid & 63, w = tid >> 6;
    const int r8 = lane >> 3, ch = lane & 7;
    const int swz = (ch ^ r8) << 3;          // pre-swizzled global chunk for linear LDS dest
    const int w512 = w << 9;                 // wave's 8-row slice within a 64-row stage call

    size_t koff = 0;
    if constexpr (MODE == 2) koff = (size_t)blockIdx.z * 2816;

    const unsigned short* Bb = B;
    if constexpr (MODE == 1) Bb += (size_t)e * (2 * MINTER) * HID;
    if constexpr (MODE == 3) Bb += (size_t)e * HID * MINTER;

    auto arow = [&](int h, int c) -> const unsigned short* {
        int rit = h * 128 + c * 64 + (w << 3) + r8;
        int grow;
        if constexpr (GATHER) {
            int idx = r0 + rit; if (idx > cnt - 1) idx = cnt - 1;
            int ent = tok_list[e * CAP + idx];
            grow = (MODE == 1) ? (ent >> 1) : ent;
        } else {
            grow = r0 + rit;
        }
        return A + (size_t)grow * STRIDE + koff + swz;
    };
    auto brow = [&](int h, int c) -> const unsigned short* {
        int rr = bn0 + h * 128 + c * 64 + (w << 3) + r8;
        return Bb + (size_t)rr * STRIDE + koff + swz;
    };
    const unsigned short *pA00 = arow(0, 0), *pA01 = arow(0, 1);
    const unsigned short *pA10 = arow(1, 0), *pA11 = arow(1, 1);
    const unsigned short *pB00 = brow(0, 0), *pB01 = brow(0, 1);
    const unsigned short *pB10 = brow(1, 0), *pB11 = brow(1, 1);

    const int m16 = lane & 15, quad = lane >> 4, m7 = m16 & 7;
    const int wm = w >> 2, wn = w & 3;
    int aoff[4], boff[2];
#pragma unroll
    for (int mt = 0; mt < 4; mt++) aoff[mt] = (wm * 64 + mt * 16 + m16) * BK;
#pragma unroll
    for (int nt = 0; nt < 2; nt++) boff[nt] = (wn * 32 + nt * 16 + m16) * BK;
    const int sl0 = ((0 * 4 + quad) ^ m7) << 3;
    const int sl1 = ((1 * 4 + quad) ^ m7) << 3;

    floatx4 acc[2][2][4][2];
#pragma unroll
    for (int i = 0; i < 2; i++)
#pragma unroll
        for (int j = 0; j < 2; j++)
#pragma unroll
            for (int mt = 0; mt < 4; mt++)
#pragma unroll
                for (int nt = 0; nt < 2; nt++)
                    acc[i][j][mt][nt] = floatx4{0.f, 0.f, 0.f, 0.f};

    // prologue: tile0 x4 regions + A0/B1/A1 of tile1 (B0[1] issued in P1(0));
    // vmcnt(10) lands A0[0],B0[0] (first 4 of 14 staged loads).
    ISS_A0(0); ISS_B0(0); ISS_B1(0); ISS_A1(0);
    ISS_A0(1); ISS_B1(1); ISS_A1(1);
    VMCNT10; BARRIER;

    for (int t = 0; t < KT; t++) {
        const int b = t & 1, nb = b ^ 1;
        const unsigned short* laA0 = smem + (b * 2 + 0) * 8192;
        const unsigned short* laA1 = smem + (b * 2 + 1) * 8192;
        const unsigned short* lbB0 = smem + 32768 + (b * 2 + 0) * 8192;
        const unsigned short* lbB1 = smem + 32768 + (b * 2 + 1) * 8192;
        bf16x8 af0[4], af1[4], bq0[2], bq1[2];

        // P1: C(0,0) -- read A0 + B0; issue B0[nb] (tile t+1; last read P4(t-1))
        LD_A(laA0); LD_B(lbB0);
        ISS_B0(nb);
        BARRIER;
        MFMA16(0, 0);
        VMCNT10; BARRIER;      // tile 0: lands B1[0]; steady state: no-op (<=8)

        // P2: C(0,1) -- reuse af(A0); read B1; issue A0[b] (tile t+2; last read P1(t))
        LD_B(lbB1);
        ISS_A0(b);
        BARRIER;
        MFMA16(0, 1);
        VMCNT10; BARRIER;      // tile 0: lands A1[0]; steady state: no-op (<=10)

        // P3: C(1,1) -- read A1; reuse bq(B1); issue B1[b] (t+2; last read P2(t))
        LD_A(laA1);
        ISS_B1(b);
        BARRIER;
        MFMA16(1, 1);
        BARRIER;

        // P4: C(1,0) -- reuse af(A1); read B0; issue A1[b] (t+2; last read P3(t))
        LD_B(lbB0);
        ISS_A1(b);
        BARRIER;
        MFMA16(1, 0);
        VMCNT6; BARRIER;       // lands tile t+1's 4 regions (ages 4-7 phases)
    }
    VMCNT0;   // drain tail prefetches before LDS dealloc / wave exit

    // ---------------- epilogues ----------------
    if constexpr (MODE == 0) {
        unsigned short* sout = (unsigned short*)outp;
#pragma unroll
        for (int qm = 0; qm < 2; qm++)
#pragma unroll
        for (int mt = 0; mt < 4; mt++) {
            const int rb = r0 + qm * 128 + wm * 64 + mt * 16 + quad * 4;
#pragma unroll
            for (int qn = 0; qn < 2; qn++)
#pragma unroll
            for (int nt = 0; nt < 2; nt++) {
                const int col = bn0 + qn * 128 + wn * 32 + nt * 16 + m16;
#pragma unroll
                for (int r = 0; r < 4; r++) {
                    float v = acc[qm][qn][mt][nt][r];
                    float o = __shfl_xor(v, 1);          // partner (gate<->up) column
                    if (!(m16 & 1))
                        sout[(size_t)(rb + r) * SINTER + (col >> 1)] =
                            f2bf_rn(v / (1.f + __expf(-v)) * o);
                }
            }
        }
    } else if constexpr (MODE == 1) {
        unsigned short* sout = (unsigned short*)outp;
#pragma unroll
        for (int qm = 0; qm < 2; qm++)
#pragma unroll
        for (int mt = 0; mt < 4; mt++) {
            const int ib = r0 + qm * 128 + wm * 64 + mt * 16 + quad * 4;
            int ent[4]; bool val[4];
#pragma unroll
            for (int r = 0; r < 4; r++) {
                val[r] = (ib + r) < cnt;
                ent[r] = val[r] ? tok_list[e * CAP + ib + r] : 0;
            }
#pragma unroll
            for (int qn = 0; qn < 2; qn++)
#pragma unroll
            for (int nt = 0; nt < 2; nt++) {
                const int col = bn0 + qn * 128 + wn * 32 + nt * 16 + m16;
#pragma unroll
                for (int r = 0; r < 4; r++) {
                    float v = acc[qm][qn][mt][nt][r];
                    float o = __shfl_xor(v, 1);
                    if (val[r] && !(m16 & 1))
                        sout[(size_t)ent[r] * MINTER + (col >> 1)] =
                            f2bf_rn(v / (1.f + __expf(-v)) * o);
                }
            }
        }
    } else if constexpr (MODE == 2) {
        float* fout = (float*)outp;
#pragma unroll
        for (int qm = 0; qm < 2; qm++)
#pragma unroll
        for (int mt = 0; mt < 4; mt++) {
            const int rb = r0 + qm * 128 + wm * 64 + mt * 16 + quad * 4;
            float gs[4];
#pragma unroll
            for (int r = 0; r < 4; r++) gs[r] = gate_sig[rb + r];
#pragma unroll
            for (int qn = 0; qn < 2; qn++)
#pragma unroll
            for (int nt = 0; nt < 2; nt++) {
                const int col = bn0 + qn * 128 + wn * 32 + nt * 16 + m16;
#pragma unroll
                for (int r = 0; r < 4; r++)
                    unsafeAtomicAdd(&fout[(size_t)(rb + r) * HID + col],
                                    acc[qm][qn][mt][nt][r] * gs[r]);
            }
        }
    } else {
        float* fout = (float*)outp;
#pragma unroll
        for (int qm = 0; qm < 2; qm++)
#pragma unroll
        for (int mt = 0; mt < 4; mt++) {
            const int ib = r0 + qm * 128 + wm * 64 + mt * 16 + quad * 4;
            int tokv[4]; float wv[4]; bool val[4];
#pragma unroll
            for (int r = 0; r < 4; r++) {
                val[r] = (ib + r) < cnt;
                if (val[r]) {
                    int ent = tok_list[e * CAP + ib + r];
                    tokv[r] = ent >> 1;
                    wv[r] = tok2w[ent];
                } else { tokv[r] = 0; wv[r] = 0.f; }
            }
#pragma unroll
            for (int qn = 0; qn < 2; qn++)
#pragma unroll
            for (int nt = 0; nt < 2; nt++) {
                const int col = bn0 + qn * 128 + wn * 32 + nt * 16 + m16;
#pragma unroll
                for (int r = 0; r < 4; r++) {
                    if (val[r])
                        unsafeAtomicAdd(&fout[(size_t)tokv[r] * HID + col],
                                        acc[qm][qn][mt][nt][r] * wv[r]);
                }
            }
        }
    }
}

extern "C" void kernel_launch(void* const* d_in, const int* in_sizes, int n_in,
                              void* d_out, int out_size, void* d_ws, size_t ws_size,
                              hipStream_t stream) {
    const float* x    = (const float*)d_in[0];
    const float* gw   = (const float*)d_in[1];
    const float* sgw  = (const float*)d_in[2];
    const float* sgup = (const float*)d_in[3];
    const float* sdwn = (const float*)d_in[4];
    const float* w13  = (const float*)d_in[5];
    const float* w2   = (const float*)d_in[6];
    float* out = (float*)d_out;

    const size_t N_SGUP = (size_t)2 * SINTER * HID;        // 23,068,672
    const size_t N_SDWN = (size_t)HID * SINTER;            // 11,534,336
    const size_t N_W13  = (size_t)NEXP * 2 * MINTER * HID; // 46,137,344
    const size_t N_W2   = (size_t)NEXP * HID * MINTER;     // 23,068,672

    char* p = (char*)d_ws;
    unsigned short* xb = (unsigned short*)p;     p += (size_t)MTOK * HID * 2;        // 16 MB
    unsigned short* inter = (unsigned short*)p;  p += (size_t)MTOK * SINTER * 2;     // 46 MB (union)
    unsigned short* wbuf = (unsigned short*)p;   p += (N_W13 + N_W2) * 2;            // 138 MB (union)
    float* tok2w = (float*)p;                    p += (size_t)MTOK * 2 * 4;
    float* gate_sig = (float*)p;                 p += (size_t)MTOK * 4;
    int* tok_list = (int*)p;                     p += (size_t)NEXP * CAP * 4;
    int* counts = (int*)p;                       p += 64;

    // phase A weight views (overwritten in phase B after shared expert is done)
    unsigned short* sgup_b = wbuf;
    unsigned short* sdwn_b = wbuf + N_SGUP;
    // phase B weight views
    unsigned short* w13_b = wbuf;
    unsigned short* w2_b  = wbuf + N_W13;

    hipMemsetAsync(counts, 0, NEXP * sizeof(int), stream);
    // out is accumulated into (MODE2 split-K + MODE3), must start at zero
    hipMemsetAsync(out, 0, (size_t)MTOK * HID * sizeof(float), stream);

    cvt_kernel<<<(MTOK * HID) / 1024, 256, 0, stream>>>(x, xb);
    router_kernel<<<MTOK / 4, 256, 0, stream>>>(x, gw, sgw, tok2w, gate_sig, counts, tok_list);

    // ---- shared expert ----
    cvt_inter_kernel<SINTER, 2 * SINTER><<<N_SGUP / 1024, 256, 0, stream>>>(sgup, sgup_b);
    cvt_kernel<<<N_SDWN / 1024, 256, 0, stream>>>(sdwn, sdwn_b);
    gemm8<HID, HID, 0><<<dim3(2 * SINTER / 256, MTOK / 256), 512, 0, stream>>>(
        xb, sgup_b, inter, nullptr, nullptr, nullptr, nullptr);
    gemm8<SINTER, 2816, 2><<<dim3(HID / 256, MTOK / 256, 2), 512, 0, stream>>>(
        inter, sdwn_b, out, nullptr, nullptr, nullptr, gate_sig);

    // ---- MoE experts (reuse wbuf + inter) ----
    cvt_inter_kernel<MINTER, 2 * MINTER><<<N_W13 / 1024, 256, 0, stream>>>(w13, w13_b);
    cvt_kernel<<<N_W2 / 1024, 256, 0, stream>>>(w2, w2_b);
    gemm8<HID, HID, 1><<<dim3(2 * MINTER / 256, CAP / 256, NEXP), 512, 0, stream>>>(
        xb, w13_b, inter, tok_list, counts, nullptr, nullptr);
    gemm8<MINTER, MINTER, 3><<<dim3(HID / 256, CAP / 256, NEXP), 512, 0, stream>>>(
        inter, w2_b, out, tok_list, counts, tok2w, nullptr);
}

// Round 4
// 1154.300 us; speedup vs baseline: 1.0547x; 1.0268x over previous
//
#include <hip/hip_runtime.h>
#include <hip/hip_bf16.h>

#define HID 2048
#define NEXP 8
#define MINTER 1408
#define SINTER 5632
#define MTOK 4096
#define CAP 4096

#define BM 128
#define BN 128
#define BK 64

typedef short bf16x8 __attribute__((ext_vector_type(8)));
typedef float floatx4 __attribute__((ext_vector_type(4)));

__device__ __forceinline__ unsigned short f2bf_rn(float f) {
    union { float f; unsigned u; } v; v.f = f;
    unsigned r = v.u + 0x7FFFu + ((v.u >> 16) & 1u);
    return (unsigned short)(r >> 16);
}

__device__ __forceinline__ unsigned pack_bf16x2(float a, float b) {
    __hip_bfloat162 h = __float22bfloat162_rn(make_float2(a, b));
    unsigned u;
    __builtin_memcpy(&u, &h, 4);
    return u;
}

// async global->LDS, 16B per lane; lds dest must be wave-uniform base (+lane*16 by HW)
__device__ __forceinline__ void async16(const unsigned short* g, unsigned short* l) {
    __builtin_amdgcn_global_load_lds(
        (const __attribute__((address_space(1))) unsigned int*)(g),
        (__attribute__((address_space(3))) unsigned int*)(l),
        16, 0, 0);
}

__device__ __forceinline__ void cvt_block(const float* s, unsigned short* d, size_t off) {
    size_t i = off + (size_t)threadIdx.x * 4;
    float4 v = *(const float4*)(s + i);
    uint2 pk;
    pk.x = pack_bf16x2(v.x, v.y);
    pk.y = pack_bf16x2(v.z, v.w);
    *(uint2*)(d + i) = pk;
}

// merged fp32->bf16 casts (1024 elements per block)
#define CVT_NX     8192     /* MTOK*HID/1024        */
#define CVT_NSGUP  22528    /* 2*SINTER*HID/1024    */
#define CVT_NSDWN  11264    /* HID*SINTER/1024      */
#define CVT_NW13   45056    /* NEXP*2*MINTER*HID/1024 */
#define CVT_NW2    22528    /* NEXP*HID*MINTER/1024 */

__global__ void cvt3_kernel(const float* __restrict__ a, const float* __restrict__ b,
                            const float* __restrict__ c,
                            unsigned short* __restrict__ da, unsigned short* __restrict__ db,
                            unsigned short* __restrict__ dc) {
    int blk = blockIdx.x;
    if (blk < CVT_NX)                    cvt_block(a, da, (size_t)blk * 1024);
    else if (blk < CVT_NX + CVT_NSGUP)   cvt_block(b, db, (size_t)(blk - CVT_NX) * 1024);
    else                                 cvt_block(c, dc, (size_t)(blk - CVT_NX - CVT_NSGUP) * 1024);
}

__global__ void cvt2_kernel(const float* __restrict__ a, const float* __restrict__ b,
                            unsigned short* __restrict__ da, unsigned short* __restrict__ db) {
    int blk = blockIdx.x;
    if (blk < CVT_NW13) cvt_block(a, da, (size_t)blk * 1024);
    else                cvt_block(b, db, (size_t)(blk - CVT_NW13) * 1024);
}

// ---------------- router + shared gate ----------------
__global__ void router_kernel(const float* __restrict__ x, const float* __restrict__ gw,
                              const float* __restrict__ sgw,
                              float* __restrict__ tok2w, float* __restrict__ gate_sig,
                              int* __restrict__ counts, int* __restrict__ tok_list) {
    int wid = threadIdx.x >> 6, lane = threadIdx.x & 63;
    int tok = blockIdx.x * 4 + wid;
    const float* xr = x + (size_t)tok * HID;
    float acc[9];
#pragma unroll
    for (int e = 0; e < 9; e++) acc[e] = 0.f;
    for (int i = lane; i < HID; i += 64) {
        float xv = xr[i];
#pragma unroll
        for (int e = 0; e < NEXP; e++) acc[e] += xv * gw[e * HID + i];
        acc[8] += xv * sgw[i];
    }
#pragma unroll
    for (int e = 0; e < 9; e++) {
#pragma unroll
        for (int off = 32; off; off >>= 1) acc[e] += __shfl_down(acc[e], off);
    }
    if (lane == 0) {
        float m = acc[0];
#pragma unroll
        for (int e = 1; e < NEXP; e++) m = fmaxf(m, acc[e]);
        float ex[NEXP]; float s = 0.f;
#pragma unroll
        for (int e = 0; e < NEXP; e++) { ex[e] = __expf(acc[e] - m); s += ex[e]; }
        int e1 = 0; float b1 = ex[0];
#pragma unroll
        for (int e = 1; e < NEXP; e++) if (ex[e] > b1) { b1 = ex[e]; e1 = e; }
        int e2 = -1; float b2 = -1.f;
#pragma unroll
        for (int e = 0; e < NEXP; e++) {
            if (e == e1) continue;
            if (ex[e] > b2) { b2 = ex[e]; e2 = e; }
        }
        float inv = 1.f / s;
        int p = atomicAdd(&counts[e1], 1);
        tok_list[e1 * CAP + p] = tok * 2;
        tok2w[tok * 2] = b1 * inv;
        p = atomicAdd(&counts[e2], 1);
        tok_list[e2 * CAP + p] = tok * 2 + 1;
        tok2w[tok * 2 + 1] = b2 * inv;
        gate_sig[tok] = 1.f / (1.f + __expf(-acc[8]));
    }
}

// ---------------- generic NT GEMM, bf16 MFMA, global_load_lds + XOR swizzle ----
// ALL modes now use the verified 3-tile (A + 2xB) 48KB / 32-MFMA-per-tile loop:
//   MODE 0: shared gate_up: B2 = up-half (+SINTER rows), silu*mul -> bf16   (K=2048)
//   MODE 1: moe w13 gathered: B2 = up-half (+MINTER rows), silu*mul -> bf16 (K=2048)
//   MODE 2: shared down WIDE: B2 = next 128 N-rows -> 128x256 out tile,
//           * sigmoid gate, plain fp32 store                                (K=5632)
//   MODE 3: moe w2 gathered WIDE: B2 = next 128 N-rows, atomicAdd * weight  (K=1408)
// LDS layout per tile: row-major 128 rows x 64 k (bf16), 128 B/row, NO pad;
// chunk (16B) position within row is XOR-swizzled by (row & 7).
template <int KDIM, int MODE>
__global__ __launch_bounds__(256, 2) void gemm_kernel(
    const unsigned short* __restrict__ A, const unsigned short* __restrict__ B,
    void* __restrict__ outp, const int* __restrict__ tok_list,
    const int* __restrict__ counts, const float* __restrict__ tok2w,
    const float* __restrict__ gate_sig)
{
    constexpr bool GATHER = (MODE == 1 || MODE == 3);
    constexpr bool WIDE = (MODE == 2 || MODE == 3);      // 256-wide N via 2 B tiles
    // offset (elements) from B tile-1 row to its partner row in tile 2
    constexpr size_t OFF2 = (MODE == 0) ? (size_t)SINTER * HID
                          : (MODE == 1) ? (size_t)MINTER * HID
                          : (size_t)128 * KDIM;

    extern __shared__ unsigned short smem[];
    unsigned short* lA = smem;                 // 128*64 bf16 = 16 KB
    unsigned short* lBg = smem + BM * BK;      // 16 KB
    unsigned short* lBu = lBg + BN * BK;       // 16 KB

    const int e = GATHER ? blockIdx.z : 0;
    int cnt = 0;
    const int r0 = blockIdx.y * BM;
    if constexpr (GATHER) {
        cnt = counts[e];
        if (r0 >= cnt) return;
    }
    const int bn0 = blockIdx.x * (WIDE ? 2 * BN : BN);
    const int tid = threadIdx.x;
    const int lane = tid & 63, wid = tid >> 6;

    const unsigned short* Bbase = B;
    if constexpr (MODE == 1) Bbase += (size_t)e * (2 * MINTER) * HID;
    if constexpr (MODE == 3) Bbase += (size_t)e * HID * MINTER;

    // staging: per wave-call, 64 lanes load 8 rows x 8 chunks (16B). lane = r8*8+ch.
    // LDS chunk position ch holds global chunk (ch ^ r8)  -> read-side swizzle (c ^ (row&7)).
    const int r8 = lane >> 3, ch = lane & 7;
    const int swz = (ch ^ r8) * 8;   // global element offset of this lane's chunk

    const unsigned short* gA[4];
    unsigned short* dA[4];
    const unsigned short* gB[4];
    unsigned short* dB[4];
#pragma unroll
    for (int j = 0; j < 4; j++) {
        const int rrow = wid * 32 + j * 8;          // call base row within tile
        int grow;
        if constexpr (GATHER) {
            int idx = min(r0 + rrow + r8, cnt - 1);
            int entry = tok_list[e * CAP + idx];
            grow = (MODE == 1) ? (entry >> 1) : entry;
        } else {
            grow = r0 + rrow + r8;
        }
        gA[j] = A + (size_t)grow * KDIM + swz;
        dA[j] = lA + rrow * BK;                     // wave-uniform
        gB[j] = Bbase + (size_t)(bn0 + rrow + r8) * KDIM + swz;
        dB[j] = lBg + rrow * BK;
    }

    const int m16 = lane & 15, quad = lane >> 4;
    const int m7 = m16 & 7;
    const int wr = (wid >> 1) * 64, wc = (wid & 1) * 64;
    const int aBase = (wr + m16) * BK;
    const int bBase = (wc + m16) * BK;

    floatx4 accG[4][4];
    floatx4 accU[4][4];
#pragma unroll
    for (int i = 0; i < 4; i++)
#pragma unroll
        for (int j = 0; j < 4; j++) {
            accG[i][j] = floatx4{0.f, 0.f, 0.f, 0.f};
            accU[i][j] = floatx4{0.f, 0.f, 0.f, 0.f};
        }

    const int KT = KDIM / BK;
    for (int kt = 0; kt < KT; kt++) {
#pragma unroll
        for (int j = 0; j < 4; j++) { async16(gA[j], dA[j]); gA[j] += BK; }
#pragma unroll
        for (int j = 0; j < 4; j++) { async16(gB[j], dB[j]); gB[j] += BK; }
#pragma unroll
        for (int j = 0; j < 4; j++) {
            async16(gB[j] + (OFF2 - BK), dB[j] + BN * BK);
        }
        __syncthreads();   // drains vmcnt -> LDS tiles complete
#pragma unroll
        for (int kk = 0; kk < 2; kk++) {
            const int so = ((kk * 4 + quad) ^ m7) * 8;   // swizzled chunk offset
            bf16x8 af[4], bg[4];
#pragma unroll
            for (int t = 0; t < 4; t++)
                af[t] = *(const bf16x8*)(lA + aBase + t * 16 * BK + so);
#pragma unroll
            for (int t = 0; t < 4; t++)
                bg[t] = *(const bf16x8*)(lBg + bBase + t * 16 * BK + so);
#pragma unroll
            for (int mt = 0; mt < 4; mt++)
#pragma unroll
                for (int nt = 0; nt < 4; nt++)
                    accG[mt][nt] = __builtin_amdgcn_mfma_f32_16x16x32_bf16(
                        af[mt], bg[nt], accG[mt][nt], 0, 0, 0);
            bf16x8 bu[4];
#pragma unroll
            for (int t = 0; t < 4; t++)
                bu[t] = *(const bf16x8*)(lBu + bBase + t * 16 * BK + so);
#pragma unroll
            for (int mt = 0; mt < 4; mt++)
#pragma unroll
                for (int nt = 0; nt < 4; nt++)
                    accU[mt][nt] = __builtin_amdgcn_mfma_f32_16x16x32_bf16(
                        af[mt], bu[nt], accU[mt][nt], 0, 0, 0);
        }
        __syncthreads();
    }

    // ---------------- epilogues ----------------
    if constexpr (MODE == 0) {
        unsigned short* sout = (unsigned short*)outp;
#pragma unroll
        for (int mt = 0; mt < 4; mt++) {
#pragma unroll
            for (int nt = 0; nt < 4; nt++) {
                int col = bn0 + wc + nt * 16 + m16;
#pragma unroll
                for (int r = 0; r < 4; r++) {
                    int row = r0 + wr + mt * 16 + quad * 4 + r;
                    float g = accG[mt][nt][r], u = accU[mt][nt][r];
                    float s = g / (1.f + __expf(-g)) * u;
                    sout[(size_t)row * SINTER + col] = f2bf_rn(s);
                }
            }
        }
    } else if constexpr (MODE == 1) {
        unsigned short* sout = (unsigned short*)outp;
#pragma unroll
        for (int mt = 0; mt < 4; mt++) {
            int ent[4]; bool val[4];
#pragma unroll
            for (int r = 0; r < 4; r++) {
                int idx = r0 + wr + mt * 16 + quad * 4 + r;
                val[r] = idx < cnt;
                ent[r] = val[r] ? tok_list[e * CAP + idx] : 0;
            }
#pragma unroll
            for (int nt = 0; nt < 4; nt++) {
                int col = bn0 + wc + nt * 16 + m16;
#pragma unroll
                for (int r = 0; r < 4; r++) {
                    if (val[r]) {
                        float g = accG[mt][nt][r], u = accU[mt][nt][r];
                        float s = g / (1.f + __expf(-g)) * u;
                        sout[(size_t)ent[r] * MINTER + col] = f2bf_rn(s);
                    }
                }
            }
        }
    } else if constexpr (MODE == 2) {
        float* fout = (float*)outp;
#pragma unroll
        for (int mt = 0; mt < 4; mt++) {
            int rowv[4]; float gs[4];
#pragma unroll
            for (int r = 0; r < 4; r++) {
                rowv[r] = r0 + wr + mt * 16 + quad * 4 + r;
                gs[r] = gate_sig[rowv[r]];
            }
#pragma unroll
            for (int nt = 0; nt < 4; nt++) {
                int col = bn0 + wc + nt * 16 + m16;
#pragma unroll
                for (int r = 0; r < 4; r++) {
                    fout[(size_t)rowv[r] * HID + col] = accG[mt][nt][r] * gs[r];
                    fout[(size_t)rowv[r] * HID + col + 128] = accU[mt][nt][r] * gs[r];
                }
            }
        }
    } else {
        float* fout = (float*)outp;
#pragma unroll
        for (int mt = 0; mt < 4; mt++) {
            int tokv[4]; float wv[4]; bool val[4];
#pragma unroll
            for (int r = 0; r < 4; r++) {
                int idx = r0 + wr + mt * 16 + quad * 4 + r;
                val[r] = idx < cnt;
                if (val[r]) {
                    int ent = tok_list[e * CAP + idx];
                    tokv[r] = ent >> 1;
                    wv[r] = tok2w[ent];
                } else { tokv[r] = 0; wv[r] = 0.f; }
            }
#pragma unroll
            for (int nt = 0; nt < 4; nt++) {
                int col = bn0 + wc + nt * 16 + m16;
#pragma unroll
                for (int r = 0; r < 4; r++) {
                    if (val[r]) {
                        unsafeAtomicAdd(&fout[(size_t)tokv[r] * HID + col],
                                        accG[mt][nt][r] * wv[r]);
                        unsafeAtomicAdd(&fout[(size_t)tokv[r] * HID + col + 128],
                                        accU[mt][nt][r] * wv[r]);
                    }
                }
            }
        }
    }
}

extern "C" void kernel_launch(void* const* d_in, const int* in_sizes, int n_in,
                              void* d_out, int out_size, void* d_ws, size_t ws_size,
                              hipStream_t stream) {
    const float* x    = (const float*)d_in[0];
    const float* gw   = (const float*)d_in[1];
    const float* sgw  = (const float*)d_in[2];
    const float* sgup = (const float*)d_in[3];
    const float* sdwn = (const float*)d_in[4];
    const float* w13  = (const float*)d_in[5];
    const float* w2   = (const float*)d_in[6];
    float* out = (float*)d_out;

    const size_t N_SGUP = (size_t)2 * SINTER * HID;   // 23,068,672
    const size_t N_W13  = (size_t)NEXP * 2 * MINTER * HID; // 46,137,344
    const size_t N_W2   = (size_t)NEXP * HID * MINTER;     // 23,068,672

    char* p = (char*)d_ws;
    unsigned short* xb = (unsigned short*)p;     p += (size_t)MTOK * HID * 2;        // 16 MB
    unsigned short* inter = (unsigned short*)p;  p += (size_t)MTOK * SINTER * 2;     // 46 MB (union)
    unsigned short* wbuf = (unsigned short*)p;   p += (N_W13 + N_W2) * 2;            // 138 MB (union)
    float* tok2w = (float*)p;                    p += (size_t)MTOK * 2 * 4;
    float* gate_sig = (float*)p;                 p += (size_t)MTOK * 4;
    int* tok_list = (int*)p;                     p += (size_t)NEXP * CAP * 4;
    int* counts = (int*)p;                       p += 64;

    // phase A weight views (overwritten in phase B after shared expert is done)
    unsigned short* sgup_b = wbuf;
    unsigned short* sdwn_b = wbuf + N_SGUP;
    // phase B weight views
    unsigned short* w13_b = wbuf;
    unsigned short* w2_b  = wbuf + N_W13;

    hipMemsetAsync(counts, 0, NEXP * sizeof(int), stream);

    const size_t lds_dual = 3 * BM * BK * sizeof(unsigned short);   // 48 KB

    // ---- phase A: input + shared-expert weights cvt (merged), router, shared expert ----
    cvt3_kernel<<<CVT_NX + CVT_NSGUP + CVT_NSDWN, 256, 0, stream>>>(
        x, sgup, sdwn, xb, sgup_b, sdwn_b);
    router_kernel<<<MTOK / 4, 256, 0, stream>>>(x, gw, sgw, tok2w, gate_sig, counts, tok_list);

    gemm_kernel<HID, 0><<<dim3(SINTER / BN, MTOK / BM), 256, lds_dual, stream>>>(
        xb, sgup_b, inter, nullptr, nullptr, nullptr, nullptr);
    gemm_kernel<SINTER, 2><<<dim3(HID / (2 * BN), MTOK / BM), 256, lds_dual, stream>>>(
        inter, sdwn_b, out, nullptr, nullptr, nullptr, gate_sig);

    // ---- phase B: MoE weights cvt (merged, reuses wbuf), expert GEMMs ----
    cvt2_kernel<<<CVT_NW13 + CVT_NW2, 256, 0, stream>>>(w13, w2, w13_b, w2_b);
    gemm_kernel<HID, 1><<<dim3(MINTER / BN, CAP / BM, NEXP), 256, lds_dual, stream>>>(
        xb, w13_b, inter, tok_list, counts, nullptr, nullptr);
    gemm_kernel<MINTER, 3><<<dim3(HID / (2 * BN), CAP / BM, NEXP), 256, lds_dual, stream>>>(
        inter, w2_b, out, tok_list, counts, tok2w, nullptr);
}